// Round 1
// baseline (4924.234 us; speedup 1.0000x reference)
//
#include <hip/hip_runtime.h>
#include <math.h>

#define VF 59
#define HF 128
#define BB 2048
#define TT 96
#define RR 4
#define NTHREADS 384

#define VP 60
#define V2P 120

// ws layout (float offsets)
#define OFF_INV  0        // 96 inv denominators
#define OFF_DWF  96       // 59 diag(Wf)
#define OFF_DWDX 160      // 59 diag(Wdx)
#define OFF_WDH  224      // 15*128*4 = 7680
#define OFF_WH   7904     // 32*59*4  = 7552
#define OFF_WF   15456    // 15*59*4  = 3540
#define OFF_WC   18996    // 30*59*4  = 7080
#define OFF_WIH  26076    // 30*384*4 = 46080
#define OFF_WHH  72156    // 32*384*4 = 49152  -> total 121308 floats (~485 KB ws)

#define LOSS_IDX (BB*TT*VF)
#define OFF_HID  (BB*TT*VF + 1)

__device__ __forceinline__ void tpack(const float* __restrict__ W, int G, int K,
                                      float* __restrict__ dst, int gtid, int gstride) {
    // dst[(k/4)*(G*4) + g*4 + (k%4)] = W[g*K + k], zero-padded to K rounded up to 4
    int KC = (K + 3) >> 2;
    int total = KC * G * 4;
    int g4 = G * 4;
    for (int i = gtid; i < total; i += gstride) {
        int kc = i / g4;
        int rem = i - kc * g4;
        int g = rem >> 2, q = rem & 3;
        int k = kc * 4 + q;
        dst[i] = (k < K) ? W[g * K + k] : 0.f;
    }
}

__global__ __launch_bounds__(256) void prep_kernel(
    const float* __restrict__ mask,
    const float* __restrict__ Wdh, const float* __restrict__ Wdx,
    const float* __restrict__ Wh,  const float* __restrict__ Wf,
    const float* __restrict__ Wc,  const float* __restrict__ Wih,
    const float* __restrict__ Whh,
    float* __restrict__ ws, float* __restrict__ loss_ptr)
{
    __shared__ float red[256];
    int blk = blockIdx.x, tid = threadIdx.x;
    if (blk < TT) {
        // inv_den[t] = 1/(sum_{b,v} mask[b,t,v] + 1e-5)
        int t = blk;
        float s = 0.f;
        for (int i = tid; i < BB * VF; i += 256) {
            int b = i / VF, v = i - b * VF;
            s += mask[(size_t)b * (TT * VF) + (size_t)t * VF + v];
        }
        red[tid] = s;
        __syncthreads();
        for (int off = 128; off > 0; off >>= 1) {
            if (tid < off) red[tid] += red[tid + off];
            __syncthreads();
        }
        if (tid == 0) ws[OFF_INV + t] = 1.f / (red[0] + 1e-5f);
    } else {
        if (blk == TT && tid == 0) loss_ptr[0] = 0.f;
        if (blk == TT && tid < VF) {
            ws[OFF_DWF + tid]  = Wf[tid * VF + tid];
            ws[OFF_DWDX + tid] = Wdx[tid * VF + tid];
        }
        int gtid = (blk - TT) * 256 + tid;
        int gstride = 64 * 256;
        tpack(Wdh, HF,     VF,     ws + OFF_WDH, gtid, gstride);
        tpack(Wh,  VF,     HF,     ws + OFF_WH,  gtid, gstride);
        tpack(Wf,  VF,     VF,     ws + OFF_WF,  gtid, gstride);
        tpack(Wc,  VF,     2 * VF, ws + OFF_WC,  gtid, gstride);
        tpack(Wih, 3 * HF, 2 * VF, ws + OFF_WIH, gtid, gstride);
        tpack(Whh, 3 * HF, HF,     ws + OFF_WHH, gtid, gstride);
    }
}

__device__ __forceinline__ float dot4(float4 w, float4 a, float acc) {
    return fmaf(w.x, a.x, fmaf(w.y, a.y, fmaf(w.z, a.z, fmaf(w.w, a.w, acc))));
}

__global__ __launch_bounds__(NTHREADS) void rits_main(
    const float* __restrict__ x, const float* __restrict__ mask, const float* __restrict__ deltas,
    const float* __restrict__ bdh, const float* __restrict__ bdx, const float* __restrict__ bh,
    const float* __restrict__ bf,  const float* __restrict__ bc,
    const float* __restrict__ bih, const float* __restrict__ bhh,
    const float* __restrict__ ws, float* __restrict__ out)
{
    __shared__ float sh[RR][HF];     // hidden state (decayed in-place each step)
    __shared__ float sd[RR][VP];     // deltas, slot 59 zero-padded
    __shared__ float sx[RR][VP];     // x_t
    __shared__ float sxh[RR][VP];    // x_h
    __shared__ float sxr[RR][VP];    // x_r, slot 59 zero-padded
    __shared__ float sgm[RR][V2P];   // [0,59)=gamma_x  [59,118)=m  [118,120)=0
    __shared__ float simp[RR][V2P];  // [0,59)=x_imp    [59,118)=m  [118,120)=0
    __shared__ float sga[RR][2*HF];  // gi+gh for r,z gates
    __shared__ float sgni[RR][HF];   // gi n-segment (+bih)
    __shared__ float sgnh[RR][HF];   // gh n-segment (+bhh)  (kept separate: n = tanh(in + r*hn))
    __shared__ float sred[NTHREADS / 64];

    const int tid = threadIdx.x;
    const int b0 = blockIdx.x * RR;

    const float4* __restrict__ pWdh = (const float4*)(ws + OFF_WDH);
    const float4* __restrict__ pWh  = (const float4*)(ws + OFF_WH);
    const float4* __restrict__ pWf  = (const float4*)(ws + OFF_WF);
    const float4* __restrict__ pWc  = (const float4*)(ws + OFF_WC);
    const float4* __restrict__ pWih = (const float4*)(ws + OFF_WIH);
    const float4* __restrict__ pWhh = (const float4*)(ws + OFF_WHH);

    for (int i = tid; i < RR * HF; i += NTHREADS) (&sh[0][0])[i] = 0.f;
    for (int i = tid; i < RR * VP; i += NTHREADS) { (&sd[0][0])[i] = 0.f; (&sxr[0][0])[i] = 0.f; }
    for (int i = tid; i < RR * V2P; i += NTHREADS) { (&sgm[0][0])[i] = 0.f; (&simp[0][0])[i] = 0.f; }
    float loss_acc = 0.f;
    __syncthreads();

    for (int t = 0; t < TT; ++t) {
        // ---- load x_t, m_t, d_t for RR rows ----
        for (int i = tid; i < RR * VF; i += NTHREADS) {
            int r = i / VF, v = i - r * VF;
            size_t a = (size_t)(b0 + r) * (TT * VF) + (size_t)t * VF + v;
            sx[r][v] = x[a];
            float m = mask[a];
            sgm[r][VF + v]  = m;
            simp[r][VF + v] = m;
            sd[r][v] = deltas[a];
        }
        __syncthreads();

        // ---- gamma_h = exp(-relu(d@WdhT+bdh));  h *= gamma_h ----
        for (int idx = tid; idx < RR * HF; idx += NTHREADS) {
            int r = idx >> 7, j = idx & (HF - 1);
            const float4* ap = (const float4*)sd[r];
            float acc = 0.f;
            #pragma unroll
            for (int kc = 0; kc < 15; ++kc)
                acc = dot4(pWdh[kc * HF + j], ap[kc], acc);
            float g = __expf(-fmaxf(acc + bdh[j], 0.f));
            sh[r][j] *= g;
        }
        __syncthreads();

        // ---- x_h = h@WhT+bh ; x_r ; gamma_x ----
        if (tid < RR * VF) {
            int r = tid / VF, v = tid - r * VF;
            const float4* ap = (const float4*)sh[r];
            float acc = 0.f;
            #pragma unroll
            for (int kc = 0; kc < 32; ++kc)
                acc = dot4(pWh[kc * VF + v], ap[kc], acc);
            float xh = acc + bh[v];
            sxh[r][v] = xh;
            float m = sgm[r][VF + v];
            sxr[r][v] = fmaf(m, sx[r][v], (1.f - m) * xh);
            sgm[r][v] = __expf(-fmaxf(fmaf(sd[r][v], ws[OFF_DWDX + v], bdx[v]), 0.f));
        }
        __syncthreads();

        // ---- xu (zero-diag), beta, x_comb, loss, x_imp ----
        if (tid < RR * VF) {
            int r = tid / VF, v = tid - r * VF;
            const float4* ap = (const float4*)sxr[r];
            float xu = 0.f;
            #pragma unroll
            for (int kc = 0; kc < 15; ++kc)
                xu = dot4(pWf[kc * VF + v], ap[kc], xu);
            xu += bf[v] - sxr[r][v] * ws[OFF_DWF + v];
            const float4* gp = (const float4*)sgm[r];
            float beta = 0.f;
            #pragma unroll
            for (int kc = 0; kc < 30; ++kc)
                beta = dot4(pWc[kc * VF + v], gp[kc], beta);
            beta += bc[v];
            float xh = sxh[r][v];
            float xc = beta * xu + (1.f - beta) * xh;
            float m = sgm[r][VF + v];
            float xv = sx[r][v];
            loss_acc += fabsf(xv - xc) * m * ws[OFF_INV + t];
            float xi = fmaf(m, xv, (1.f - m) * xc);
            simp[r][v] = xi;
            out[(size_t)(b0 + r) * (TT * VF) + (size_t)t * VF + v] = xi;
        }
        __syncthreads();

        // ---- GRU gates: gi = [x_imp,m]@WihT, gh = h@WhhT (thread = column g, 4 row accums) ----
        {
            int g = tid;  // 384 columns, 384 threads
            float accI[RR] = {0.f, 0.f, 0.f, 0.f};
            float accH[RR] = {0.f, 0.f, 0.f, 0.f};
            #pragma unroll 6
            for (int kc = 0; kc < 30; ++kc) {
                float4 w = pWih[kc * 384 + g];
                #pragma unroll
                for (int r = 0; r < RR; ++r)
                    accI[r] = dot4(w, ((const float4*)simp[r])[kc], accI[r]);
            }
            #pragma unroll 8
            for (int kc = 0; kc < 32; ++kc) {
                float4 w = pWhh[kc * 384 + g];
                #pragma unroll
                for (int r = 0; r < RR; ++r)
                    accH[r] = dot4(w, ((const float4*)sh[r])[kc], accH[r]);
            }
            float bi = bih[g], bh2 = bhh[g];
            if (g < 2 * HF) {
                #pragma unroll
                for (int r = 0; r < RR; ++r) sga[r][g] = accI[r] + accH[r] + bi + bh2;
            } else {
                int j = g - 2 * HF;
                #pragma unroll
                for (int r = 0; r < RR; ++r) { sgni[r][j] = accI[r] + bi; sgnh[r][j] = accH[r] + bh2; }
            }
        }
        __syncthreads();

        // ---- gate math, h update, hidden write ----
        for (int idx = tid; idx < RR * HF; idx += NTHREADS) {
            int r = idx >> 7, j = idx & (HF - 1);
            float rr_ = 1.f / (1.f + __expf(-sga[r][j]));
            float zz  = 1.f / (1.f + __expf(-sga[r][HF + j]));
            float nx  = fmaf(rr_, sgnh[r][j], sgni[r][j]);
            float cl  = fminf(fmaxf(nx, -15.f), 15.f);
            float e   = __expf(-2.f * cl);
            float nn  = (1.f - e) / (1.f + e);     // tanh
            float hold = sh[r][j];
            float hnew = fmaf(zz, hold - nn, nn);  // (1-z)*n + z*h
            sh[r][j] = hnew;
            out[OFF_HID + (size_t)(b0 + r) * (TT * HF) + (size_t)t * HF + j] = hnew;
        }
        __syncthreads();
    }

    // ---- loss reduction: per-thread partials already scaled by inv_den[t] ----
    float vsum = loss_acc;
    for (int off = 32; off > 0; off >>= 1) vsum += __shfl_down(vsum, off);
    if ((tid & 63) == 0) sred[tid >> 6] = vsum;
    __syncthreads();
    if (tid == 0) {
        float s = 0.f;
        #pragma unroll
        for (int i = 0; i < NTHREADS / 64; ++i) s += sred[i];
        atomicAdd(out + LOSS_IDX, s);
    }
}

extern "C" void kernel_launch(void* const* d_in, const int* in_sizes, int n_in,
                              void* d_out, int out_size, void* d_ws, size_t ws_size,
                              hipStream_t stream) {
    const float* x      = (const float*)d_in[0];
    const float* mask   = (const float*)d_in[1];
    const float* deltas = (const float*)d_in[2];
    const float* Wdh    = (const float*)d_in[3];
    const float* bdh    = (const float*)d_in[4];
    const float* Wdx    = (const float*)d_in[5];
    const float* bdx    = (const float*)d_in[6];
    const float* Wh     = (const float*)d_in[7];
    const float* bh     = (const float*)d_in[8];
    const float* Wf     = (const float*)d_in[9];
    const float* bf     = (const float*)d_in[10];
    const float* Wc     = (const float*)d_in[11];
    const float* bc     = (const float*)d_in[12];
    const float* Wih    = (const float*)d_in[13];
    const float* Whh    = (const float*)d_in[14];
    const float* bih    = (const float*)d_in[15];
    const float* bhh    = (const float*)d_in[16];
    float* out = (float*)d_out;
    float* ws  = (float*)d_ws;

    prep_kernel<<<TT + 64, 256, 0, stream>>>(mask, Wdh, Wdx, Wh, Wf, Wc, Wih, Whh,
                                             ws, out + LOSS_IDX);
    rits_main<<<BB / RR, NTHREADS, 0, stream>>>(x, mask, deltas, bdh, bdx, bh, bf, bc,
                                                bih, bhh, ws, out);
}

// Round 2
// 1069.445 us; speedup vs baseline: 4.6045x; 4.6045x over previous
//
#include <hip/hip_runtime.h>
#include <hip/hip_bf16.h>
#include <math.h>

#define VF 59
#define HF 128
#define BB 2048
#define TT 96
#define MR 16              // batch rows per block (one MFMA M-tile)
#define NBLK (BB / MR)     // 128 blocks
#define NTH 512            // 8 waves

typedef __attribute__((ext_vector_type(8))) short short8;   // 8 x bf16 (4 VGPR)
typedef __attribute__((ext_vector_type(4))) float f32x4;    // MFMA accumulator

#define MFMA(a, b, c) __builtin_amdgcn_mfma_f32_16x16x32_bf16((a), (b), (c), 0, 0, 0)

// ---------------- ws layout ----------------
// float region
#define WF_INV   0          // 96: 1/(sum(mask_t)+1e-5)
#define WF_DWDX  96         // 59: diag(Wdx)
#define WF_END   160
// bf16 (ushort) region — B-operand fragments, streaming order:
//   frag[(tile*KS + ks)*64 + lane] = 8 bf16: W[tile*16+(lane&15)][ks*32+(lane>>4)*8 + j]
#define U_B1  (WF_END * 2)        // Wdh  [128][59]  tiles=8,  KS=2 -> 8192
#define U_B2  (U_B1 + 8192)       // Wh   [59][128]  tiles=4,  KS=4 -> 8192
#define U_B3  (U_B2 + 8192)       // Wf   [59][59]   tiles=4,  KS=2 -> 4096 (diag zeroed)
#define U_B4  (U_B3 + 4096)       // Wc   [59][118]  tiles=4,  KS=4 -> 8192
#define U_B5  (U_B4 + 8192)       // Wih  [384][118] tiles=24, KS=4 -> 49152
#define U_B6  (U_B5 + 49152)      // Whh  [384][128] tiles=24, KS=4 -> 49152

#define LOSS_IDX (BB * TT * VF)
#define OFF_HID  (BB * TT * VF + 1)

// ---------------- LDS layout ----------------
// ushort offsets (A-operand bf16 buffers; row pitch 72/136 -> 2-way bank aliasing = free)
#define S_AD    0                 // d_t      [16][72]  (k 0..58 valid, 59..63 zero)
#define S_AH    1152              // h_decay  [16][136] (k 0..127)
#define S_AXR   3328              // x_r      [16][72]
#define S_AGM   4480              // [gx|m]   [16][136] (0..58 gx, 59..117 m, 118..127 zero)
#define S_AIM0  6656              // [ximp|m] [16][136] double-buffered (parity t&1)
#define S_AIM1  8832
// float offsets (= ushort/2), fp32 scratch
#define F_SHV   5504              // h state fp32 [16][128]
#define F_SX    7552              // x_t  [16][60]
#define F_SM    8512              // m_t  [16][60]
#define F_SXH   9472              // x_h  [16][64]
#define F_SXR   10496             // x_r  [16][64]
#define F_SB    11520             // beta [16][64]
#define F_RED   12544             // 8 loss partials
#define F_TOT   12552             // ~50 KB LDS

__device__ __forceinline__ ushort f2bf(float f) {
    __hip_bfloat16 h = __float2bfloat16(f);
    return *reinterpret_cast<ushort*>(&h);
}
__device__ __forceinline__ float sigm(float v) { return 1.f / (1.f + __expf(-v)); }
__device__ __forceinline__ float tanh_f(float v) {
    float c = fminf(fmaxf(v, -15.f), 15.f);
    float e = __expf(-2.f * c);
    return (1.f - e) / (1.f + e);
}

// ---------------- prep: inv_den + diag + B-fragment packing ----------------
__device__ void packB(const float* __restrict__ W, int G, int K, int tiles, int KS,
                      int zdiag, ushort* __restrict__ dst, int gtid, int gstride) {
    int total = tiles * KS * 512;
    for (int idx = gtid; idx < total; idx += gstride) {
        int j  = idx & 7;
        int l  = (idx >> 3) & 63;
        int tk = idx >> 9;            // tile*KS + ks
        int ks = tk % KS;
        int tile = tk / KS;
        int g = tile * 16 + (l & 15);
        int k = ks * 32 + ((l >> 4) << 3) + j;
        float v = 0.f;
        if (g < G && k < K) v = W[g * K + k];
        if (zdiag && g == k) v = 0.f;
        dst[idx] = f2bf(v);
    }
}

__global__ __launch_bounds__(256) void prep_kernel(
    const float* __restrict__ mask,
    const float* __restrict__ Wdh, const float* __restrict__ Wdx,
    const float* __restrict__ Wh,  const float* __restrict__ Wf,
    const float* __restrict__ Wc,  const float* __restrict__ Wih,
    const float* __restrict__ Whh,
    float* __restrict__ ws, float* __restrict__ loss_ptr)
{
    __shared__ float red[256];
    int blk = blockIdx.x, tid = threadIdx.x;
    if (blk < TT) {
        int t = blk;
        float s = 0.f;
        for (int i = tid; i < BB * VF; i += 256) {
            int b = i / VF, v = i - b * VF;
            s += mask[(size_t)b * (TT * VF) + (size_t)t * VF + v];
        }
        red[tid] = s;
        __syncthreads();
        for (int off = 128; off > 0; off >>= 1) {
            if (tid < off) red[tid] += red[tid + off];
            __syncthreads();
        }
        if (tid == 0) ws[WF_INV + t] = 1.f / (red[0] + 1e-5f);
    } else {
        if (blk == TT && tid == 0) loss_ptr[0] = 0.f;
        if (blk == TT && tid < VF) ws[WF_DWDX + tid] = Wdx[tid * VF + tid];
        ushort* wsu = (ushort*)ws;
        int gtid = (blk - TT) * 256 + tid;
        int gstride = 64 * 256;
        packB(Wdh, HF,     VF,     8,  2, 0, wsu + U_B1, gtid, gstride);
        packB(Wh,  VF,     HF,     4,  4, 0, wsu + U_B2, gtid, gstride);
        packB(Wf,  VF,     VF,     4,  2, 1, wsu + U_B3, gtid, gstride);
        packB(Wc,  VF,     2*VF,   4,  4, 0, wsu + U_B4, gtid, gstride);
        packB(Wih, 3*HF,   2*VF,   24, 4, 0, wsu + U_B5, gtid, gstride);
        packB(Whh, 3*HF,   HF,     24, 4, 0, wsu + U_B6, gtid, gstride);
    }
}

// ---------------- main recurrence ----------------
__global__ __launch_bounds__(NTH) void rits_main(
    const float* __restrict__ x, const float* __restrict__ mask, const float* __restrict__ deltas,
    const float* __restrict__ bdh, const float* __restrict__ bdx, const float* __restrict__ bh,
    const float* __restrict__ bf,  const float* __restrict__ bc,
    const float* __restrict__ bih, const float* __restrict__ bhh,
    const float* __restrict__ ws, float* __restrict__ out)
{
    __shared__ __align__(16) float smf[F_TOT];
    ushort* smu = (ushort*)smf;

    const int tid  = threadIdx.x;
    const int lane = tid & 63;
    const int w    = tid >> 6;         // wave 0..7
    const int ln15 = lane & 15;
    const int quad = lane >> 4;
    const int b0   = blockIdx.x * MR;

    const ushort* wsu = (const ushort*)ws;
    const short8* B1 = (const short8*)(wsu + U_B1);
    const short8* B2 = (const short8*)(wsu + U_B2);
    const short8* B3 = (const short8*)(wsu + U_B3);
    const short8* B4 = (const short8*)(wsu + U_B4);
    const short8* B5 = (const short8*)(wsu + U_B5);
    const short8* B6 = (const short8*)(wsu + U_B6);

    // hoisted per-thread constants (indices fixed across t)
    const int jH = w * 16 + ln15;                    // hidden col for P1/P4
    const float c_bdh = bdh[jH];
    const float c_br  = bih[jH]       + bhh[jH];         // r-gate bias sum
    const float c_bz  = bih[jH + 128] + bhh[jH + 128];   // z-gate bias sum
    const float c_bin = bih[jH + 256];
    const float c_bhn = bhh[jH + 256];
    const int vC = (w < 4 ? w : w - 4) * 16 + ln15;  // feature col for P2/P3
    const float c_bh = (vC < VF) ? bh[vC] : 0.f;
    const float c_bf = (vC < VF) ? bf[vC] : 0.f;
    const float c_bc = (vC < VF) ? bc[vC] : 0.f;

    // zero LDS (pads must be zero; h0 = 0)
    for (int i = tid; i < F_TOT; i += NTH) smf[i] = 0.f;
    __syncthreads();

    // load t=0 inputs (all threads)
    for (int it = 0; it < 6; ++it) {
        int idx = tid + it * NTH;
        if (idx < 3 * MR * VF) {
            int arr = idx / (MR * VF);
            int rem = idx - arr * (MR * VF);
            int r = rem / VF, v = rem - r * VF;
            size_t a = (size_t)(b0 + r) * (TT * VF) + v;
            if (arr == 0) smf[F_SX + r * 60 + v] = x[a];
            else if (arr == 1) {
                float mv = mask[a];
                smf[F_SM + r * 60 + v] = mv;
                ushort mb = f2bf(mv);
                smu[S_AGM  + r * 136 + 59 + v] = mb;
                smu[S_AIM0 + r * 136 + 59 + v] = mb;
            } else {
                float dv = deltas[a];
                smu[S_AD + r * 72 + v] = f2bf(dv);
                float gx = __expf(-fmaxf(fmaf(dv, ws[WF_DWDX + v], bdx[v]), 0.f));
                smu[S_AGM + r * 136 + v] = f2bf(gx);
            }
        }
    }
    __syncthreads();

    float loss_acc = 0.f;

    for (int t = 0; t < TT; ++t) {
        // ---- P1: gamma_h = exp(-relu(d@WdhT+bdh)); h *= gamma_h. wave w -> tile w ----
        {
            short8 a0 = *(const short8*)(smu + S_AD + ln15 * 72 + quad * 8);
            short8 a1 = *(const short8*)(smu + S_AD + ln15 * 72 + quad * 8 + 32);
            f32x4 acc = {0.f, 0.f, 0.f, 0.f};
            acc = MFMA(a0, B1[(w * 2 + 0) * 64 + lane], acc);
            acc = MFMA(a1, B1[(w * 2 + 1) * 64 + lane], acc);
            #pragma unroll
            for (int i = 0; i < 4; ++i) {
                int m = quad * 4 + i;
                float g  = __expf(-fmaxf(acc[i] + c_bdh, 0.f));
                float hd = smf[F_SHV + m * 128 + jH] * g;
                smf[F_SHV + m * 128 + jH] = hd;
                smu[S_AH + m * 136 + jH] = f2bf(hd);
            }
        }
        __syncthreads();

        // ---- P2: waves 0-3: x_h GEMM; waves 4-7: beta GEMM (independent) ----
        if (w < 4) {
            f32x4 acc = {0.f, 0.f, 0.f, 0.f};
            #pragma unroll
            for (int ks = 0; ks < 4; ++ks) {
                short8 a = *(const short8*)(smu + S_AH + ln15 * 136 + quad * 8 + ks * 32);
                acc = MFMA(a, B2[(w * 4 + ks) * 64 + lane], acc);
            }
            if (vC < VF) {
                #pragma unroll
                for (int i = 0; i < 4; ++i) {
                    int m = quad * 4 + i;
                    float xh = acc[i] + c_bh;
                    smf[F_SXH + m * 64 + vC] = xh;
                    float mm = smf[F_SM + m * 60 + vC];
                    float xr = fmaf(mm, smf[F_SX + m * 60 + vC], (1.f - mm) * xh);
                    smf[F_SXR + m * 64 + vC] = xr;
                    smu[S_AXR + m * 72 + vC] = f2bf(xr);
                }
            }
        } else {
            f32x4 acc = {0.f, 0.f, 0.f, 0.f};
            #pragma unroll
            for (int ks = 0; ks < 4; ++ks) {
                short8 a = *(const short8*)(smu + S_AGM + ln15 * 136 + quad * 8 + ks * 32);
                acc = MFMA(a, B4[((w - 4) * 4 + ks) * 64 + lane], acc);
            }
            if (vC < VF) {
                #pragma unroll
                for (int i = 0; i < 4; ++i)
                    smf[F_SB + (quad * 4 + i) * 64 + vC] = acc[i] + c_bc;
            }
        }
        __syncthreads();

        // ---- P3: waves 0-3: xu GEMM + combine/loss/x_imp; waves 4-7: prefetch t+1 ----
        float pref[12];
        if (w < 4) {
            short8 a0 = *(const short8*)(smu + S_AXR + ln15 * 72 + quad * 8);
            short8 a1 = *(const short8*)(smu + S_AXR + ln15 * 72 + quad * 8 + 32);
            f32x4 acc = {0.f, 0.f, 0.f, 0.f};
            acc = MFMA(a0, B3[(w * 2 + 0) * 64 + lane], acc);
            acc = MFMA(a1, B3[(w * 2 + 1) * 64 + lane], acc);
            if (vC < VF) {
                const int aimW = S_AIM0 + (t & 1) * 2176;
                float idt = ws[WF_INV + t];
                #pragma unroll
                for (int i = 0; i < 4; ++i) {
                    int m = quad * 4 + i;
                    float xu   = acc[i] + c_bf;          // Wf diag zeroed at pack time
                    float beta = smf[F_SB  + m * 64 + vC];
                    float xh   = smf[F_SXH + m * 64 + vC];
                    float xc   = beta * xu + (1.f - beta) * xh;
                    float mm   = smf[F_SM + m * 60 + vC];
                    float xv   = smf[F_SX + m * 60 + vC];
                    loss_acc += fabsf(xv - xc) * mm * idt;
                    float xi = fmaf(mm, xv, (1.f - mm) * xc);
                    out[(size_t)(b0 + m) * (TT * VF) + (size_t)t * VF + vC] = xi;
                    smu[aimW + m * 136 + vC] = f2bf(xi);
                }
            }
        } else if (t + 1 < TT) {
            int q = tid - 256;
            #pragma unroll
            for (int it = 0; it < 12; ++it) {
                int idx = q + it * 256;
                if (idx < 3 * MR * VF) {
                    int arr = idx / (MR * VF);
                    int rem = idx - arr * (MR * VF);
                    int r = rem / VF, v = rem - r * VF;
                    const float* src = arr == 0 ? x : (arr == 1 ? mask : deltas);
                    pref[it] = src[(size_t)(b0 + r) * (TT * VF) + (size_t)(t + 1) * VF + v];
                }
            }
        }
        __syncthreads();

        // ---- P4: gh + gi GEMMs, gates in-register (wave w -> tiles w, w+8, w+16) ----
        {
            const int aimR = S_AIM0 + (t & 1) * 2176;
            short8 ah[4], ai[4];
            #pragma unroll
            for (int ks = 0; ks < 4; ++ks) {
                ah[ks] = *(const short8*)(smu + S_AH + ln15 * 136 + quad * 8 + ks * 32);
                ai[ks] = *(const short8*)(smu + aimR + ln15 * 136 + quad * 8 + ks * 32);
            }
            f32x4 gI[3], gH[3];
            #pragma unroll
            for (int tt = 0; tt < 3; ++tt) { gI[tt] = (f32x4){0.f,0.f,0.f,0.f}; gH[tt] = (f32x4){0.f,0.f,0.f,0.f}; }
            #pragma unroll
            for (int tt = 0; tt < 3; ++tt) {
                int tile = w + tt * 8;
                #pragma unroll
                for (int ks = 0; ks < 4; ++ks) {
                    gI[tt] = MFMA(ai[ks], B5[(tile * 4 + ks) * 64 + lane], gI[tt]);
                    gH[tt] = MFMA(ah[ks], B6[(tile * 4 + ks) * 64 + lane], gH[tt]);
                }
            }
            #pragma unroll
            for (int i = 0; i < 4; ++i) {
                int m = quad * 4 + i;
                float r_ = sigm(gI[0][i] + gH[0][i] + c_br);
                float z_ = sigm(gI[1][i] + gH[1][i] + c_bz);
                float hn = gH[2][i] + c_bhn;
                float n_ = tanh_f(fmaf(r_, hn, gI[2][i] + c_bin));
                float hd = smf[F_SHV + m * 128 + jH];
                float hnew = fmaf(z_, hd - n_, n_);      // (1-z)*n + z*h
                smf[F_SHV + m * 128 + jH] = hnew;
                out[OFF_HID + (size_t)(b0 + m) * (TT * HF) + (size_t)t * HF + jH] = hnew;
            }
        }
        // P4 tail: waves 4-7 write prefetched t+1 inputs (buffers not read in P4)
        if (w >= 4 && t + 1 < TT) {
            int q = tid - 256;
            const int aimN = S_AIM0 + ((t + 1) & 1) * 2176;
            #pragma unroll
            for (int it = 0; it < 12; ++it) {
                int idx = q + it * 256;
                if (idx < 3 * MR * VF) {
                    int arr = idx / (MR * VF);
                    int rem = idx - arr * (MR * VF);
                    int r = rem / VF, v = rem - r * VF;
                    float val = pref[it];
                    if (arr == 0) smf[F_SX + r * 60 + v] = val;
                    else if (arr == 1) {
                        smf[F_SM + r * 60 + v] = val;
                        ushort mb = f2bf(val);
                        smu[S_AGM + r * 136 + 59 + v] = mb;
                        smu[aimN  + r * 136 + 59 + v] = mb;
                    } else {
                        smu[S_AD + r * 72 + v] = f2bf(val);
                        float gx = __expf(-fmaxf(fmaf(val, ws[WF_DWDX + v], bdx[v]), 0.f));
                        smu[S_AGM + r * 136 + v] = f2bf(gx);
                    }
                }
            }
        }
        __syncthreads();
    }

    // ---- loss reduction ----
    float vsum = loss_acc;
    for (int off = 32; off > 0; off >>= 1) vsum += __shfl_down(vsum, off);
    if (lane == 0) smf[F_RED + w] = vsum;
    __syncthreads();
    if (tid == 0) {
        float s = 0.f;
        #pragma unroll
        for (int i = 0; i < 8; ++i) s += smf[F_RED + i];
        atomicAdd(out + LOSS_IDX, s);
    }
}

extern "C" void kernel_launch(void* const* d_in, const int* in_sizes, int n_in,
                              void* d_out, int out_size, void* d_ws, size_t ws_size,
                              hipStream_t stream) {
    const float* x      = (const float*)d_in[0];
    const float* mask   = (const float*)d_in[1];
    const float* deltas = (const float*)d_in[2];
    const float* Wdh    = (const float*)d_in[3];
    const float* bdh    = (const float*)d_in[4];
    const float* Wdx    = (const float*)d_in[5];
    const float* bdx    = (const float*)d_in[6];
    const float* Wh     = (const float*)d_in[7];
    const float* bh     = (const float*)d_in[8];
    const float* Wf     = (const float*)d_in[9];
    const float* bf     = (const float*)d_in[10];
    const float* Wc     = (const float*)d_in[11];
    const float* bc     = (const float*)d_in[12];
    const float* Wih    = (const float*)d_in[13];
    const float* Whh    = (const float*)d_in[14];
    const float* bih    = (const float*)d_in[15];
    const float* bhh    = (const float*)d_in[16];
    float* out = (float*)d_out;
    float* ws  = (float*)d_ws;

    prep_kernel<<<TT + 64, 256, 0, stream>>>(mask, Wdh, Wdx, Wh, Wf, Wc, Wih, Whh,
                                             ws, out + LOSS_IDX);
    rits_main<<<NBLK, NTH, 0, stream>>>(x, mask, deltas, bdh, bdx, bh, bf, bc,
                                        bih, bhh, ws, out);
}

// Round 3
// 801.318 us; speedup vs baseline: 6.1452x; 1.3346x over previous
//
#include <hip/hip_runtime.h>
#include <hip/hip_bf16.h>
#include <math.h>

#define VF 59
#define HF 128
#define BB 2048
#define TT 96
#define MR 16              // batch rows per block (one MFMA M-tile)
#define NBLK (BB / MR)     // 128 blocks
#define NTH 512            // 8 waves

typedef __attribute__((ext_vector_type(8))) short short8;   // 8 x bf16 (4 VGPR)
typedef __attribute__((ext_vector_type(4))) float f32x4;    // MFMA accumulator

#define MFMA(a, b, c) __builtin_amdgcn_mfma_f32_16x16x32_bf16((a), (b), (c), 0, 0, 0)

// ---------------- ws layout ----------------
// float region
#define WF_INV   0          // 96: 1/(sum(mask_t)+1e-5)  (finalized in prep_pack)
#define WF_ACC   96         // 96: atomic accumulators (zeroed in prep_zero)
#define WF_DWDX  192        // 59: diag(Wdx)
#define WF_END   256
// bf16 (ushort) region — B-operand fragments:
//   frag[(tile*KS + ks)*64 + lane] = 8 bf16: W[tile*16+(lane&15)][ks*32+(lane>>4)*8 + j]
#define U_B1  (WF_END * 2)        // Wdh  [128][59]  tiles=8,  KS=2 -> 8192
#define U_B2  (U_B1 + 8192)       // Wh   [59][128]  tiles=4,  KS=4 -> 8192
#define U_B3  (U_B2 + 8192)       // Wf   [59][59]   tiles=4,  KS=2 -> 4096 (diag zeroed)
#define U_B4  (U_B3 + 4096)       // Wc   [59][118]  tiles=4,  KS=4 -> 8192
#define U_B5  (U_B4 + 8192)       // Wih  [384][118] tiles=24, KS=4 -> 49152
#define U_B6  (U_B5 + 49152)      // Whh  [384][128] tiles=24, KS=4 -> 49152

#define LOSS_IDX (BB * TT * VF)
#define OFF_HID  (BB * TT * VF + 1)

// ---------------- LDS layout ----------------
// ushort offsets (bf16 A-operand buffers)
#define S_AD    0                 // d_t      [16][72]
#define S_AH    1152              // h_decay  [16][136]
#define S_AXR   3328              // x_r      [16][72]
#define S_AGM   4480              // [gx|m]   [16][136]
#define S_AIM0  6656              // [ximp|m] [16][136] double-buffered (parity t&1)
#define S_AIM1  8832              // end 11008 ushorts
// float offsets (= ushort idx / 2)
#define F_SX    5504              // x_t  [16][60]
#define F_SM    6464              // m_t  [16][60]
#define F_SXH   7424              // x_h  [16][64]
#define F_SB    8448              // beta [16][64]
#define F_RED   9472              // 8 loss partials
#define F_GXP   9480              // [0,59) diag(Wdx), [64,123) bdx
#define F_TOT   9608              // ~38.4 KB LDS

__device__ __forceinline__ ushort f2bf(float f) {
    __hip_bfloat16 h = __float2bfloat16(f);
    return *reinterpret_cast<ushort*>(&h);
}
__device__ __forceinline__ float sigm(float v) { return 1.f / (1.f + __expf(-v)); }
__device__ __forceinline__ float tanh_f(float v) {
    float c = fminf(fmaxf(v, -15.f), 15.f);
    float e = __expf(-2.f * c);
    return (1.f - e) / (1.f + e);
}

// ---------------- prep 1: zero accumulators ----------------
__global__ __launch_bounds__(128) void prep_zero(float* __restrict__ ws, float* __restrict__ loss_ptr) {
    int tid = threadIdx.x;
    if (tid < TT) ws[WF_ACC + tid] = 0.f;
    if (tid == 96) loss_ptr[0] = 0.f;
}

// ---------------- prep 2: streaming per-t mask sums ----------------
__global__ __launch_bounds__(256) void prep_acc(const float* __restrict__ mask, float* __restrict__ ws) {
    __shared__ float acc[TT];
    int tid = threadIdx.x;
    if (tid < TT) acc[tid] = 0.f;
    __syncthreads();
    #pragma unroll
    for (int rr = 0; rr < 2; ++rr) {
        int row = blockIdx.x * 512 + rr * 256 + tid;    // row = b*TT + t, rows = BB*TT
        const float* p = mask + (size_t)row * VF;
        float s = 0.f;
        #pragma unroll
        for (int v = 0; v < VF; ++v) s += p[v];
        atomicAdd(&acc[row % TT], s);
    }
    __syncthreads();
    if (tid < TT) atomicAdd(&ws[WF_ACC + tid], acc[tid]);
}

// ---------------- prep 3: pack B fragments + finalize ----------------
__device__ void packB(const float* __restrict__ W, int G, int K, int tiles, int KS,
                      int zdiag, ushort* __restrict__ dst, int gtid, int gstride) {
    int total = tiles * KS * 512;
    for (int idx = gtid; idx < total; idx += gstride) {
        int j  = idx & 7;
        int l  = (idx >> 3) & 63;
        int tk = idx >> 9;
        int ks = tk % KS;
        int tile = tk / KS;
        int g = tile * 16 + (l & 15);
        int k = ks * 32 + ((l >> 4) << 3) + j;
        float v = 0.f;
        if (g < G && k < K) v = W[g * K + k];
        if (zdiag && g == k) v = 0.f;
        dst[idx] = f2bf(v);
    }
}

__global__ __launch_bounds__(256) void prep_pack(
    const float* __restrict__ Wdh, const float* __restrict__ Wdx,
    const float* __restrict__ Wh,  const float* __restrict__ Wf,
    const float* __restrict__ Wc,  const float* __restrict__ Wih,
    const float* __restrict__ Whh, float* __restrict__ ws)
{
    int blk = blockIdx.x, tid = threadIdx.x;
    if (blk == 64) {
        if (tid < TT) ws[WF_INV + tid] = 1.f / (ws[WF_ACC + tid] + 1e-5f);
        if (tid < VF) ws[WF_DWDX + tid] = Wdx[tid * VF + tid];
        return;
    }
    ushort* wsu = (ushort*)ws;
    int gtid = blk * 256 + tid;
    int gstride = 64 * 256;
    packB(Wdh, HF,     VF,     8,  2, 0, wsu + U_B1, gtid, gstride);
    packB(Wh,  VF,     HF,     4,  4, 0, wsu + U_B2, gtid, gstride);
    packB(Wf,  VF,     VF,     4,  2, 1, wsu + U_B3, gtid, gstride);
    packB(Wc,  VF,     2*VF,   4,  4, 0, wsu + U_B4, gtid, gstride);
    packB(Wih, 3*HF,   2*VF,   24, 4, 0, wsu + U_B5, gtid, gstride);
    packB(Whh, 3*HF,   HF,     24, 4, 0, wsu + U_B6, gtid, gstride);
}

// ---------------- main recurrence ----------------
__global__ __launch_bounds__(NTH, 2) void rits_main(
    const float* __restrict__ x, const float* __restrict__ mask, const float* __restrict__ deltas,
    const float* __restrict__ bdh, const float* __restrict__ bdx, const float* __restrict__ bh,
    const float* __restrict__ bf,  const float* __restrict__ bc,
    const float* __restrict__ bih, const float* __restrict__ bhh,
    const float* __restrict__ ws, float* __restrict__ out)
{
    __shared__ __align__(16) float smf[F_TOT];
    ushort* smu = (ushort*)smf;

    const int tid  = threadIdx.x;
    const int lane = tid & 63;
    const int w    = tid >> 6;         // wave 0..7
    const int ln15 = lane & 15;
    const int quad = lane >> 4;
    const int b0   = blockIdx.x * MR;

    const ushort* wsu = (const ushort*)ws;
    const short8* B1 = (const short8*)(wsu + U_B1);
    const short8* B2 = (const short8*)(wsu + U_B2);
    const short8* B3 = (const short8*)(wsu + U_B3);
    const short8* B4 = (const short8*)(wsu + U_B4);
    const short8* B5 = (const short8*)(wsu + U_B5);
    const short8* B6 = (const short8*)(wsu + U_B6);

    // ---- hoist ALL weight fragments into registers (t-invariant) ----
    short8 wB1[2];
    #pragma unroll
    for (int i = 0; i < 2; ++i) wB1[i] = B1[(w * 2 + i) * 64 + lane];
    short8 wB24[4];
    #pragma unroll
    for (int ks = 0; ks < 4; ++ks)
        wB24[ks] = (w < 4) ? B2[(w * 4 + ks) * 64 + lane]
                           : B4[((w - 4) * 4 + ks) * 64 + lane];
    short8 wB3[2];
    #pragma unroll
    for (int i = 0; i < 2; ++i) wB3[i] = B3[(((w < 4) ? w : (w - 4)) * 2 + i) * 64 + lane];
    short8 wB5[12], wB6[12];
    #pragma unroll
    for (int tt = 0; tt < 3; ++tt)
        #pragma unroll
        for (int ks = 0; ks < 4; ++ks) {
            wB5[tt * 4 + ks] = B5[((w + tt * 8) * 4 + ks) * 64 + lane];
            wB6[tt * 4 + ks] = B6[((w + tt * 8) * 4 + ks) * 64 + lane];
        }

    // hoisted per-thread bias constants
    const int jH = w * 16 + ln15;
    const float c_bdh = bdh[jH];
    const float c_br  = bih[jH]       + bhh[jH];
    const float c_bz  = bih[jH + 128] + bhh[jH + 128];
    const float c_bin = bih[jH + 256];
    const float c_bhn = bhh[jH + 256];
    const int vC = (w < 4 ? w : w - 4) * 16 + ln15;
    const float c_bh = (vC < VF) ? bh[vC] : 0.f;
    const float c_bf = (vC < VF) ? bf[vC] : 0.f;
    const float c_bc = (vC < VF) ? bc[vC] : 0.f;

    float hreg[4] = {0.f, 0.f, 0.f, 0.f};   // h state lives in registers (P1/P4 share (m,jH) mapping)

    // zero LDS (pads must be zero)
    for (int i = tid; i < F_TOT; i += NTH) smf[i] = 0.f;
    __syncthreads();

    // t=0 inputs + gamma-x params into LDS
    if (tid < VF) { smf[F_GXP + tid] = ws[WF_DWDX + tid]; smf[F_GXP + 64 + tid] = bdx[tid]; }
    for (int it = 0; it < 6; ++it) {
        int idx = tid + it * NTH;
        if (idx < 3 * MR * VF) {
            int arr = idx / (MR * VF);
            int rem = idx - arr * (MR * VF);
            int r = rem / VF, v = rem - r * VF;
            size_t a = (size_t)(b0 + r) * (TT * VF) + v;
            if (arr == 0) smf[F_SX + r * 60 + v] = x[a];
            else if (arr == 1) {
                float mv = mask[a];
                smf[F_SM + r * 60 + v] = mv;
                ushort mb = f2bf(mv);
                smu[S_AGM  + r * 136 + 59 + v] = mb;
                smu[S_AIM0 + r * 136 + 59 + v] = mb;
            } else {
                float dv = deltas[a];
                smu[S_AD + r * 72 + v] = f2bf(dv);
                float gx = __expf(-fmaxf(fmaf(dv, ws[WF_DWDX + v], bdx[v]), 0.f));
                smu[S_AGM + r * 136 + v] = f2bf(gx);
            }
        }
    }
    __syncthreads();

    float loss_acc = 0.f;

    for (int t = 0; t < TT; ++t) {
        // ---- prefetch t+1 inputs early (waves 4-7): 3 phases of slack ----
        float pref[12];
        if (w >= 4 && t + 1 < TT) {
            int q = tid - 256;
            #pragma unroll
            for (int it = 0; it < 12; ++it) {
                int idx = q + it * 256;
                if (idx < 3 * MR * VF) {
                    int arr = idx / (MR * VF);
                    int rem = idx - arr * (MR * VF);
                    int r = rem / VF, v = rem - r * VF;
                    const float* src = arr == 0 ? x : (arr == 1 ? mask : deltas);
                    pref[it] = src[(size_t)(b0 + r) * (TT * VF) + (size_t)(t + 1) * VF + v];
                }
            }
        }

        // ---- P1: gamma_h GEMM; h *= gamma_h (registers); write h_decay bf16 ----
        {
            short8 a0 = *(const short8*)(smu + S_AD + ln15 * 72 + quad * 8);
            short8 a1 = *(const short8*)(smu + S_AD + ln15 * 72 + quad * 8 + 32);
            f32x4 acc = {0.f, 0.f, 0.f, 0.f};
            acc = MFMA(a0, wB1[0], acc);
            acc = MFMA(a1, wB1[1], acc);
            #pragma unroll
            for (int i = 0; i < 4; ++i) {
                int m = quad * 4 + i;
                float g  = __expf(-fmaxf(acc[i] + c_bdh, 0.f));
                float hd = hreg[i] * g;
                hreg[i] = hd;
                smu[S_AH + m * 136 + jH] = f2bf(hd);
            }
        }
        __syncthreads();

        // ---- P2: waves 0-3: x_h GEMM; waves 4-7: beta GEMM ----
        if (w < 4) {
            f32x4 acc = {0.f, 0.f, 0.f, 0.f};
            #pragma unroll
            for (int ks = 0; ks < 4; ++ks) {
                short8 a = *(const short8*)(smu + S_AH + ln15 * 136 + quad * 8 + ks * 32);
                acc = MFMA(a, wB24[ks], acc);
            }
            if (vC < VF) {
                #pragma unroll
                for (int i = 0; i < 4; ++i) {
                    int m = quad * 4 + i;
                    float xh = acc[i] + c_bh;
                    smf[F_SXH + m * 64 + vC] = xh;
                    float mm = smf[F_SM + m * 60 + vC];
                    float xr = fmaf(mm, smf[F_SX + m * 60 + vC], (1.f - mm) * xh);
                    smu[S_AXR + m * 72 + vC] = f2bf(xr);
                }
            }
        } else {
            f32x4 acc = {0.f, 0.f, 0.f, 0.f};
            #pragma unroll
            for (int ks = 0; ks < 4; ++ks) {
                short8 a = *(const short8*)(smu + S_AGM + ln15 * 136 + quad * 8 + ks * 32);
                acc = MFMA(a, wB24[ks], acc);
            }
            if (vC < VF) {
                #pragma unroll
                for (int i = 0; i < 4; ++i)
                    smf[F_SB + (quad * 4 + i) * 64 + vC] = acc[i] + c_bc;
            }
        }
        __syncthreads();

        // ---- P3: waves 0-3: xu GEMM + combine/loss/x_imp ----
        if (w < 4) {
            short8 a0 = *(const short8*)(smu + S_AXR + ln15 * 72 + quad * 8);
            short8 a1 = *(const short8*)(smu + S_AXR + ln15 * 72 + quad * 8 + 32);
            f32x4 acc = {0.f, 0.f, 0.f, 0.f};
            acc = MFMA(a0, wB3[0], acc);
            acc = MFMA(a1, wB3[1], acc);
            if (vC < VF) {
                const int aimW = S_AIM0 + (t & 1) * 2176;
                float idt = ws[WF_INV + t];
                #pragma unroll
                for (int i = 0; i < 4; ++i) {
                    int m = quad * 4 + i;
                    float xu   = acc[i] + c_bf;          // Wf diag zeroed at pack time
                    float beta = smf[F_SB  + m * 64 + vC];
                    float xh   = smf[F_SXH + m * 64 + vC];
                    float xc   = beta * xu + (1.f - beta) * xh;
                    float mm   = smf[F_SM + m * 60 + vC];
                    float xv   = smf[F_SX + m * 60 + vC];
                    loss_acc += fabsf(xv - xc) * mm * idt;
                    float xi = fmaf(mm, xv, (1.f - mm) * xc);
                    out[(size_t)(b0 + m) * (TT * VF) + (size_t)t * VF + vC] = xi;
                    smu[aimW + m * 136 + vC] = f2bf(xi);
                }
            }
        }
        __syncthreads();

        // ---- P4: gi + gh GEMMs (register weights), gates, h update ----
        {
            const int aimR = S_AIM0 + (t & 1) * 2176;
            short8 ah[4], ai[4];
            #pragma unroll
            for (int ks = 0; ks < 4; ++ks) {
                ah[ks] = *(const short8*)(smu + S_AH + ln15 * 136 + quad * 8 + ks * 32);
                ai[ks] = *(const short8*)(smu + aimR + ln15 * 136 + quad * 8 + ks * 32);
            }
            f32x4 gI[3], gH[3];
            #pragma unroll
            for (int tt = 0; tt < 3; ++tt) { gI[tt] = (f32x4){0.f,0.f,0.f,0.f}; gH[tt] = (f32x4){0.f,0.f,0.f,0.f}; }
            #pragma unroll
            for (int tt = 0; tt < 3; ++tt)
                #pragma unroll
                for (int ks = 0; ks < 4; ++ks) {
                    gI[tt] = MFMA(ai[ks], wB5[tt * 4 + ks], gI[tt]);
                    gH[tt] = MFMA(ah[ks], wB6[tt * 4 + ks], gH[tt]);
                }
            #pragma unroll
            for (int i = 0; i < 4; ++i) {
                int m = quad * 4 + i;
                float r_ = sigm(gI[0][i] + gH[0][i] + c_br);
                float z_ = sigm(gI[1][i] + gH[1][i] + c_bz);
                float hn = gH[2][i] + c_bhn;
                float n_ = tanh_f(fmaf(r_, hn, gI[2][i] + c_bin));
                float hnew = fmaf(z_, hreg[i] - n_, n_);
                hreg[i] = hnew;
                out[OFF_HID + (size_t)(b0 + m) * (TT * HF) + (size_t)t * HF + jH] = hnew;
            }
        }
        // P4 tail: waves 4-7 commit prefetched t+1 inputs
        if (w >= 4 && t + 1 < TT) {
            int q = tid - 256;
            const int aimN = S_AIM0 + ((t + 1) & 1) * 2176;
            #pragma unroll
            for (int it = 0; it < 12; ++it) {
                int idx = q + it * 256;
                if (idx < 3 * MR * VF) {
                    int arr = idx / (MR * VF);
                    int rem = idx - arr * (MR * VF);
                    int r = rem / VF, v = rem - r * VF;
                    float val = pref[it];
                    if (arr == 0) smf[F_SX + r * 60 + v] = val;
                    else if (arr == 1) {
                        smf[F_SM + r * 60 + v] = val;
                        ushort mb = f2bf(val);
                        smu[S_AGM + r * 136 + 59 + v] = mb;
                        smu[aimN  + r * 136 + 59 + v] = mb;
                    } else {
                        smu[S_AD + r * 72 + v] = f2bf(val);
                        float gx = __expf(-fmaxf(fmaf(val, smf[F_GXP + v], smf[F_GXP + 64 + v]), 0.f));
                        smu[S_AGM + r * 136 + v] = f2bf(gx);
                    }
                }
            }
        }
        __syncthreads();
    }

    // ---- loss reduction ----
    float vsum = loss_acc;
    for (int off = 32; off > 0; off >>= 1) vsum += __shfl_down(vsum, off);
    if (lane == 0) smf[F_RED + w] = vsum;
    __syncthreads();
    if (tid == 0) {
        float s = 0.f;
        #pragma unroll
        for (int i = 0; i < 8; ++i) s += smf[F_RED + i];
        atomicAdd(out + LOSS_IDX, s);
    }
}

extern "C" void kernel_launch(void* const* d_in, const int* in_sizes, int n_in,
                              void* d_out, int out_size, void* d_ws, size_t ws_size,
                              hipStream_t stream) {
    const float* x      = (const float*)d_in[0];
    const float* mask   = (const float*)d_in[1];
    const float* deltas = (const float*)d_in[2];
    const float* Wdh    = (const float*)d_in[3];
    const float* bdh    = (const float*)d_in[4];
    const float* Wdx    = (const float*)d_in[5];
    const float* bdx    = (const float*)d_in[6];
    const float* Wh     = (const float*)d_in[7];
    const float* bh     = (const float*)d_in[8];
    const float* Wf     = (const float*)d_in[9];
    const float* bf     = (const float*)d_in[10];
    const float* Wc     = (const float*)d_in[11];
    const float* bc     = (const float*)d_in[12];
    const float* Wih    = (const float*)d_in[13];
    const float* Whh    = (const float*)d_in[14];
    const float* bih    = (const float*)d_in[15];
    const float* bhh    = (const float*)d_in[16];
    float* out = (float*)d_out;
    float* ws  = (float*)d_ws;

    prep_zero<<<1, 128, 0, stream>>>(ws, out + LOSS_IDX);
    prep_acc<<<384, 256, 0, stream>>>(mask, ws);
    prep_pack<<<65, 256, 0, stream>>>(Wdh, Wdx, Wh, Wf, Wc, Wih, Whh, ws);
    rits_main<<<NBLK, NTH, 0, stream>>>(x, mask, deltas, bdh, bdx, bh, bf, bc,
                                        bih, bhh, ws, out);
}